// Round 2
// baseline (1366.009 us; speedup 1.0000x reference)
//
#include <hip/hip_runtime.h>
#include <hip/hip_bf16.h>

#define NN 500000
#define NE 1500000
#define BATCH 64
#define LSEQ 512
#define HDIM 64
#define CCONV 64

// ---------------- zero a float region ----------------
__global__ void k_zero(float* __restrict__ p, int n) {
    int i = blockIdx.x * blockDim.x + threadIdx.x;
    int stride = gridDim.x * blockDim.x;
    for (; i < n; i += stride) p[i] = 0.0f;
}

// ---------------- degree / dinv ----------------
__global__ void k_fill1(float* __restrict__ d, int n) {
    int i = blockIdx.x * blockDim.x + threadIdx.x;
    if (i < n) d[i] = 1.0f;
}

__global__ void k_degcount(const int* __restrict__ dst, float* __restrict__ deg, int e_cnt) {
    int e = blockIdx.x * blockDim.x + threadIdx.x;
    if (e < e_cnt) atomicAdd(&deg[dst[e]], 1.0f);
}

__global__ void k_rsqrt(float* __restrict__ d, int n) {
    int i = blockIdx.x * blockDim.x + threadIdx.x;
    if (i < n) d[i] = rsqrtf(d[i]);
}

// ---------------- layer 1 init: bufB = dinv^2 * (x@W1) + b1 ----------------
__global__ void k_init1(const float* __restrict__ x, const float* __restrict__ W1,
                        const float* __restrict__ b1, const float* __restrict__ dinv,
                        float* __restrict__ bufB) {
    int lane = threadIdx.x & 63;
    int wave = (blockIdx.x * blockDim.x + threadIdx.x) >> 6;
    int nwaves = (gridDim.x * blockDim.x) >> 6;
    float w0 = W1[lane], w1 = W1[64 + lane], bj = b1[lane];
    for (int n = wave; n < NN; n += nwaves) {
        float x0 = x[2 * n], x1 = x[2 * n + 1];
        float xw = x0 * w0 + x1 * w1;
        float dv = dinv[n];
        bufB[n * 64 + lane] = dv * dv * xw + bj;
    }
}

// ---------------- layer-1 edge scatter: xw[src] recomputed on the fly ----------------
__global__ void k_scatter1(const int* __restrict__ src, const int* __restrict__ dst,
                           const float* __restrict__ dinv, const float* __restrict__ x,
                           const float* __restrict__ W1, float* __restrict__ bufB) {
    int lane = threadIdx.x & 63;
    int wave = (blockIdx.x * blockDim.x + threadIdx.x) >> 6;
    int nwaves = (gridDim.x * blockDim.x) >> 6;
    float w0 = W1[lane], w1 = W1[64 + lane];
    for (int e = wave; e < NE; e += nwaves) {
        int s = src[e], d = dst[e];
        float x0 = x[2 * s], x1 = x[2 * s + 1];     // broadcast loads
        float w = dinv[s] * dinv[d];
        float v = w * (x0 * w0 + x1 * w1);
        atomicAdd(&bufB[d * 64 + lane], v);
    }
}

// ---------- layer 2: h = relu(bufB); xw2 = h@W2 -> bf16; bufB = dinv^2*xw2 + b2 ----------
__global__ void k_gemm2(const float* __restrict__ W2, const float* __restrict__ b2,
                        const float* __restrict__ dinv,
                        float* __restrict__ bufB, __hip_bfloat16* __restrict__ bufA16) {
    int lane = threadIdx.x & 63;
    int wave = (blockIdx.x * blockDim.x + threadIdx.x) >> 6;
    int nwaves = (gridDim.x * blockDim.x) >> 6;
    float wcol[64];
#pragma unroll
    for (int k = 0; k < 64; ++k) wcol[k] = W2[k * 64 + lane];
    float bj = b2[lane];
    for (int n = wave; n < NN; n += nwaves) {
        const float4* hp = (const float4*)(bufB + n * 64);
        float acc = 0.0f;
#pragma unroll
        for (int kk = 0; kk < 16; ++kk) {
            float4 h = hp[kk];
            acc += fmaxf(h.x, 0.0f) * wcol[4 * kk + 0]
                 + fmaxf(h.y, 0.0f) * wcol[4 * kk + 1]
                 + fmaxf(h.z, 0.0f) * wcol[4 * kk + 2]
                 + fmaxf(h.w, 0.0f) * wcol[4 * kk + 3];
        }
        float dv = dinv[n];
        bufA16[n * 64 + lane] = __float2bfloat16(acc);
        bufB[n * 64 + lane] = dv * dv * acc + bj;  // row n owned by this wave: safe
    }
}

// ---------------- layer-2 edge scatter: gather bf16 xw2[src] ----------------
__global__ void k_scatter2(const int* __restrict__ src, const int* __restrict__ dst,
                           const float* __restrict__ dinv,
                           const __hip_bfloat16* __restrict__ bufA16,
                           float* __restrict__ bufB) {
    int lane = threadIdx.x & 63;
    int wave = (blockIdx.x * blockDim.x + threadIdx.x) >> 6;
    int nwaves = (gridDim.x * blockDim.x) >> 6;
    for (int e = wave; e < NE; e += nwaves) {
        int s = src[e], d = dst[e];
        float w = dinv[s] * dinv[d];
        float v = w * __bfloat162float(bufA16[s * 64 + lane]);
        atomicAdd(&bufB[d * 64 + lane], v);
    }
}

// ---------------- pool: segment sum/max/count keyed by batch*L+depth ----------------
__global__ void k_pool(const float* __restrict__ bufB, const int* __restrict__ batch,
                       const int* __restrict__ depth, float* __restrict__ sum,
                       unsigned int* __restrict__ mx, float* __restrict__ cnt) {
    int lane = threadIdx.x & 63;
    int wave = (blockIdx.x * blockDim.x + threadIdx.x) >> 6;
    int nwaves = (gridDim.x * blockDim.x) >> 6;
    for (int n = wave; n < NN; n += nwaves) {
        float v = fmaxf(bufB[n * 64 + lane], 0.0f);  // relu fused here
        int seg = batch[n] * LSEQ + depth[n];
        atomicAdd(&sum[seg * 64 + lane], v);
        atomicMax(&mx[seg * 64 + lane], __float_as_uint(v));  // v >= 0
        if (lane == 0) atomicAdd(&cnt[seg], 1.0f);
    }
}

// ---------------- conv1d(k=3,pad=1) + relu + partial mean over L ----------------
__global__ __launch_bounds__(256) void k_conv(const float* __restrict__ sum,
                                              const float* __restrict__ mxf,
                                              const float* __restrict__ cnt,
                                              const float* __restrict__ cw,
                                              const float* __restrict__ cb,
                                              float* __restrict__ pooled) {
    __shared__ float s_seq[66 * 129];  // rows padded to 129 -> conflict-free
    int b = blockIdx.x >> 3;
    int l0 = (blockIdx.x & 7) * 64;
    int tid = threadIdx.x;
    for (int idx = tid; idx < 66 * 128; idx += 256) {
        int r = idx >> 7, i = idx & 127;
        int l = l0 + r - 1;
        float v = 0.0f;
        if (l >= 0 && l < LSEQ) {
            int seg = b * LSEQ + l;
            if (i < 64) v = sum[seg * 64 + i] / fmaxf(cnt[seg], 1.0f);
            else        v = mxf[seg * 64 + (i - 64)];
        }
        s_seq[r * 129 + i] = v;
    }
    __syncthreads();
    int l_local = tid & 63;
    int wid = tid >> 6;
    for (int rep = 0; rep < 16; ++rep) {
        int c = __builtin_amdgcn_readfirstlane(wid + 4 * rep);  // wave-uniform channel
        const float* wc = cw + c * 384;                          // scalar loads
        float acc = cb[c];
#pragma unroll
        for (int kk = 0; kk < 3; ++kk) {
            const float* sr = s_seq + (l_local + kk) * 129;
#pragma unroll 8
            for (int i = 0; i < 128; ++i)
                acc += sr[i] * wc[i * 3 + kk];
        }
        float y = fmaxf(acc, 0.0f);
#pragma unroll
        for (int off = 32; off; off >>= 1) y += __shfl_xor(y, off, 64);
        if (l_local == 0) atomicAdd(&pooled[b * 64 + c], y);
    }
}

// ---------------- head: mean -> fc1+relu -> fc2 -> sigmoid ----------------
__global__ void k_head(const float* __restrict__ pooled, const float* __restrict__ f1w,
                       const float* __restrict__ f1b, const float* __restrict__ f2w,
                       const float* __restrict__ f2b, float* __restrict__ out) {
    int b = blockIdx.x;
    int j = threadIdx.x;
    const float invL = 1.0f / (float)LSEQ;
    float z = f1b[j];
    for (int c = 0; c < 64; ++c)
        z += (pooled[b * 64 + c] * invL) * f1w[c * 64 + j];
    z = fmaxf(z, 0.0f);
    float v = z * f2w[j];
#pragma unroll
    for (int off = 32; off; off >>= 1) v += __shfl_xor(v, off, 64);
    if (j == 0) out[b] = 1.0f / (1.0f + expf(-(v + f2b[0])));
}

extern "C" void kernel_launch(void* const* d_in, const int* in_sizes, int n_in,
                              void* d_out, int out_size, void* d_ws, size_t ws_size,
                              hipStream_t stream) {
    const float* x     = (const float*)d_in[0];
    const int*   ei    = (const int*)d_in[1];
    const int*   depth = (const int*)d_in[2];
    const int*   batch = (const int*)d_in[3];
    const float* W1    = (const float*)d_in[4];
    const float* b1    = (const float*)d_in[5];
    const float* W2    = (const float*)d_in[6];
    const float* b2    = (const float*)d_in[7];
    const float* cw    = (const float*)d_in[8];
    const float* cb    = (const float*)d_in[9];
    const float* f1w   = (const float*)d_in[10];
    const float* f1b   = (const float*)d_in[11];
    const float* f2w   = (const float*)d_in[12];
    const float* f2b   = (const float*)d_in[13];
    float* out = (float*)d_out;

    // workspace layout (total ~211 MB)
    float* ws    = (float*)d_ws;
    float* dinv  = ws;                                   // NN f32          (2 MB)
    float* bufB  = ws + NN;                              // NN*64 f32       (128 MB)
    float* sumb  = bufB + (size_t)NN * 64;               // 32768*64 f32    (8.4 MB)
    float* mxb   = sumb + BATCH * LSEQ * 64;             // 32768*64 uint   (8.4 MB)
    float* cntb  = mxb + BATCH * LSEQ * 64;              // 32768 f32
    float* pool  = cntb + BATCH * LSEQ;                  // 4096 f32
    __hip_bfloat16* bufA16 = (__hip_bfloat16*)(pool + BATCH * 64);  // NN*64 bf16 (64 MB)

    const int* src = ei;
    const int* dst = ei + NE;

    // zero pool-state region (sum|max|cnt|pooled are contiguous floats)
    int zn = BATCH * LSEQ * 64 * 2 + BATCH * LSEQ + BATCH * 64;
    k_zero<<<2048, 256, 0, stream>>>(sumb, zn);

    // degree -> dinv
    k_fill1<<<(NN + 255) / 256, 256, 0, stream>>>(dinv, NN);
    k_degcount<<<(NE + 255) / 256, 256, 0, stream>>>(dst, dinv, NE);
    k_rsqrt<<<(NN + 255) / 256, 256, 0, stream>>>(dinv, NN);

    // layer 1
    k_init1<<<2048, 256, 0, stream>>>(x, W1, b1, dinv, bufB);
    k_scatter1<<<2048, 256, 0, stream>>>(src, dst, dinv, x, W1, bufB);

    // layer 2
    k_gemm2<<<2048, 256, 0, stream>>>(W2, b2, dinv, bufB, bufA16);
    k_scatter2<<<2048, 256, 0, stream>>>(src, dst, dinv, bufA16, bufB);

    // pool
    k_pool<<<2048, 256, 0, stream>>>(bufB, batch, depth, sumb, (unsigned int*)mxb, cntb);

    // conv + partial mean
    k_conv<<<BATCH * 8, 256, 0, stream>>>(sumb, mxb, cntb, cw, cb, pool);

    // head
    k_head<<<BATCH, 64, 0, stream>>>(pool, f1w, f1b, f2w, f2b, out);
}